// Round 1
// 600.963 us; speedup vs baseline: 1.0617x; 1.0617x over previous
//
#include <hip/hip_runtime.h>
#include <math.h>

#define NATOM 2048
#define CD 128
#define SD 2
#define TT 512
#define CTD 384
#define NBI 3
#define MR 4096  // SD*NATOM

typedef unsigned short ushortx;
typedef __attribute__((ext_vector_type(8))) short bf16x8;
typedef __attribute__((ext_vector_type(4))) float f32x4;
typedef __attribute__((ext_vector_type(4))) unsigned short us4;

__device__ __forceinline__ float sigm(float x){ return 1.0f/(1.0f+expf(-x)); }
__device__ __forceinline__ ushortx f2b(float f){
  union { float f; unsigned u; } v; v.f = f;
  unsigned r = v.u + 0x7fffu + ((v.u>>16)&1u);
  return (ushortx)(r>>16);
}
__device__ __forceinline__ float b2f(ushortx u){
  union { unsigned u; float f; } v; v.u = ((unsigned)u)<<16; return v.f;
}
union U8 { ushortx u[8]; float4 v; };

__device__ __forceinline__ void unpack8(float* dst, float4 v){
  U8 pk; pk.v = v;
  #pragma unroll
  for (int t=0;t<8;t++) dst[t] = b2f(pk.u[t]);
}

// ---- workspace layout (byte offsets, 256-aligned) ----
#define OFFB_W3T    0ll        // ushort 6*384*128   [n][k] [gate|shift|og]
#define OFFB_B3     589824ll   // f32 6*384
#define OFFB_WQKVGT 599040ll   // ushort 3*512*128
#define OFFB_BQ     992256ll   // f32 3*512
#define OFFB_WOUTT  998400ll   // ushort 3*128*128
#define OFFB_WABT   1096704ll  // ushort 3*512*128
#define OFFB_WTOUTT 1489920ll  // ushort 3*128*256
#define OFFB_WTOKT  1686528ll  // ushort 384*128
#define OFFB_A1     1784832ll  // ushort 4096*128 (attention og output)
#define OFFB_SNP    2833408ll  // ushort 6*2048*384 (bf16)
#define OFFB_A      12270592ll // f32 4096*128
#define OFFB_QKVG   14367744ll // ushort 4096*512 (bf16)
#define OFFB_ZB     18562048ll // ushort 3*8*2048*128 (bf16)
#define OFFB_QTOK   31144960ll // f32 4096*384

struct WPtrs {
  const float *aln_gate_w, *aln_gate_b, *aln_shift_w, *og_w, *og_b;
  const float *t_aln_gate_w, *t_aln_gate_b, *t_aln_shift_w, *t_og_w, *t_og_b;
  const float *q_w, *q_b, *k_w, *v_w, *gate_w, *out_w;
  const float *t_a_w, *t_b_w, *t_out_w, *tok_w;
};

// merged prologue: weight pack (blocks 0..3470) + atom_single copy (3471..5518)
// + zb compute (5519..6542). All independent of each other.
__global__ __launch_bounds__(256) void prologue_kernel(WPtrs P, char* __restrict__ wsb,
  const float* __restrict__ atom_single, const float* __restrict__ atom_pair,
  const float* __restrict__ plw, const float* __restrict__ plb, const float* __restrict__ pw)
{
  int b = blockIdx.x;
  if (b < 3471){
    long long idx = (long long)b*256 + threadIdx.x;
    const long long s0=294912, s1=2304, s2=196608, s3=1536, s4=49152, s5=196608, s6=98304;
    if (idx < s0) { // W3T[which][n][k]
      int which = (int)(idx/49152); int r = (int)(idx%49152); int n=r/128, k=r%128;
      int i = which>>1, t = which&1;
      const float* src;
      if (n<128)      src = (t?P.t_aln_gate_w :P.aln_gate_w ) + i*16384 + k*128 + n;
      else if (n<256) src = (t?P.t_aln_shift_w:P.aln_shift_w) + i*16384 + k*128 + (n-128);
      else            src = (t?P.t_og_w       :P.og_w       ) + i*16384 + k*128 + (n-256);
      ((ushortx*)(wsb+OFFB_W3T))[idx] = f2b(*src); return;
    }
    idx -= s0;
    if (idx < s1) {
      int which = (int)(idx/384); int col = (int)(idx%384); int i=which>>1, t=which&1;
      float v = 0.f;
      if (col<128)       v = (t?P.t_aln_gate_b:P.aln_gate_b)[i*128+col];
      else if (col>=256) v = (t?P.t_og_b      :P.og_b      )[i*128+col-256];
      ((float*)(wsb+OFFB_B3))[idx] = v; return;
    }
    idx -= s1;
    if (idx < s2) { // WQKVGT[i][n][k]
      int i = (int)(idx/65536); int r = (int)(idx%65536); int n=r/128, k=r%128;
      int seg = n>>7, c = n&127;
      const float* src = (seg==0?P.q_w: seg==1?P.k_w: seg==2?P.v_w: P.gate_w) + i*16384 + k*128 + c;
      ((ushortx*)(wsb+OFFB_WQKVGT))[idx] = f2b(*src); return;
    }
    idx -= s2;
    if (idx < s3) {
      int i = (int)(idx/512); int col = (int)(idx%512);
      ((float*)(wsb+OFFB_BQ))[idx] = (col<128) ? P.q_b[i*128+col] : 0.f; return;
    }
    idx -= s3;
    if (idx < s4) { // WOUTT
      int i = (int)(idx/16384); int r = (int)(idx%16384); int n=r/128, k=r%128;
      ((ushortx*)(wsb+OFFB_WOUTT))[idx] = f2b(P.out_w[i*16384 + k*128 + n]); return;
    }
    idx -= s4;
    if (idx < s5) { // WABT
      int i = (int)(idx/65536); int r = (int)(idx%65536); int n=r/128, k=r%128;
      const float* src = (n<256) ? P.t_a_w + i*32768 + k*256 + n
                                 : P.t_b_w + i*32768 + k*256 + (n-256);
      ((ushortx*)(wsb+OFFB_WABT))[idx] = f2b(*src); return;
    }
    idx -= s5;
    if (idx < s6) { // WTOUTT
      int i = (int)(idx/32768); int r = (int)(idx%32768); int n=r/256, k=r%256;
      ((ushortx*)(wsb+OFFB_WTOUTT))[idx] = f2b(P.t_out_w[i*32768 + k*128 + n]); return;
    }
    idx -= s6;
    { // WTOKT
      int n = (int)(idx/128); int k = (int)(idx%128);
      ((ushortx*)(wsb+OFFB_WTOKT))[idx] = f2b(P.tok_w[k*384 + n]); return;
    }
  }
  if (b < 5519){
    int i = (b-3471)*256 + threadIdx.x;
    ((float*)(wsb+OFFB_A))[i] = atom_single[i];
    return;
  }
  // zb part: zb_all[it][h][q][j] bf16, j in [0,128): key m = (q&~31)-48+j
  {
    int idx = (b-5519)*256 + threadIdx.x;
    int q = idx>>7, j = idx&127;
    int m = (q & ~31) - 48 + j;
    bool ok = (m>=0 && m<NATOM);
    float x[16]; float mu=0.f, rs=0.f;
    if (ok){
      float s=0.f, sq=0.f;
      const float* p = atom_pair + ((long long)q*NATOM + m)*16;
      #pragma unroll
      for (int c=0;c<16;c++){ x[c]=p[c]; s+=x[c]; sq+=x[c]*x[c]; }
      mu = s*(1.f/16.f); float var = sq*(1.f/16.f)-mu*mu; rs = rsqrtf(var+1e-5f);
    }
    ushortx* zb = (ushortx*)(wsb+OFFB_ZB);
    #pragma unroll
    for (int it=0; it<NBI; it++){
      float out[8] = {0,0,0,0,0,0,0,0};
      if (ok){
        #pragma unroll
        for (int c=0;c<16;c++){
          float xn = (x[c]-mu)*rs*plw[it*16+c] + plb[it*16+c];
          #pragma unroll
          for (int h=0;h<8;h++) out[h] += xn * pw[it*128 + c*8 + h];
        }
      }
      #pragma unroll
      for (int h=0;h<8;h++)
        zb[(((long long)it*8+h)*NATOM + q)*128 + j] = f2b(out[h]);
    }
  }
}

// banded attention + fused output gate; qkvg and zb are bf16
__global__ __launch_bounds__(256) void attn_kernel(const ushortx* __restrict__ qkvg,
  const ushortx* __restrict__ zb, const float* __restrict__ mask, ushortx* __restrict__ og)
{
  int qb = blockIdx.x, h = blockIdx.y, s = blockIdx.z;
  int base = qb*32 - 48;
  __shared__ float Qs[32][20], Ks[128][20], Vs[128][20], Ls[32][132], maskb[128];
  __shared__ float redx[32][8], rowv[32];
  int tid = threadIdx.x;
  for (int idx=tid; idx<32*2; idx+=256){
    int r=idx>>1, d8=(idx&1)*8;
    float4 v = *(const float4*)&qkvg[((long long)(s*NATOM + qb*32 + r))*512 + h*16 + d8];
    unpack8(&Qs[r][d8], v);
  }
  for (int idx=tid; idx<512; idx+=256){
    int j = idx&127, d8 = ((idx>>7)&1)*8, kv = idx>>8;
    int m = base + j; int mc = m<0?0:(m>NATOM-1?NATOM-1:m);
    long long row = ((long long)(s*NATOM + mc))*512;
    float4 v = *(const float4*)&qkvg[row + (kv?256:128) + h*16 + d8];
    if (kv) unpack8(&Vs[j][d8], v); else unpack8(&Ks[j][d8], v);
  }
  if (tid < 128){
    int m = base + tid;
    maskb[tid] = (m>=0 && m<NATOM) ? (mask[m]-1.0f)*1e8f : -1e30f;
  }
  __syncthreads();
  int r = tid>>3, g = tid&7;
  {
    float4 q0=*(float4*)&Qs[r][0], q1=*(float4*)&Qs[r][4], q2=*(float4*)&Qs[r][8], q3=*(float4*)&Qs[r][12];
    const ushortx* zrow = zb + ((long long)h*NATOM + (qb*32+r))*128;
    #pragma unroll
    for (int j=g; j<128; j+=8){
      float4 k0=*(float4*)&Ks[j][0], k1=*(float4*)&Ks[j][4], k2=*(float4*)&Ks[j][8], k3=*(float4*)&Ks[j][12];
      float dot = q0.x*k0.x + q0.y*k0.y + q0.z*k0.z + q0.w*k0.w
                + q1.x*k1.x + q1.y*k1.y + q1.z*k1.z + q1.w*k1.w
                + q2.x*k2.x + q2.y*k2.y + q2.z*k2.z + q2.w*k2.w
                + q3.x*k3.x + q3.y*k3.y + q3.z*k3.z + q3.w*k3.w;
      Ls[r][j] = dot*0.25f + b2f(zrow[j]) + maskb[j];
    }
  }
  __syncthreads();
  float pmax = -1e30f;
  for (int j=g*16; j<g*16+16; j++) pmax = fmaxf(pmax, Ls[r][j]);
  redx[r][g] = pmax; __syncthreads();
  if (g==0){ float mx=redx[r][0]; for(int u=1;u<8;u++) mx=fmaxf(mx,redx[r][u]); rowv[r]=mx; }
  __syncthreads();
  float mx = rowv[r];
  float psum = 0.f;
  for (int j=g*16; j<g*16+16; j++){ float e = expf(Ls[r][j]-mx); Ls[r][j]=e; psum += e; }
  redx[r][g] = psum; __syncthreads();
  if (g==0){ float sm=0.f; for(int u=0;u<8;u++) sm+=redx[r][u]; rowv[r]=sm; }
  __syncthreads();
  {
    int q2=tid>>3, dg=(tid>>1)&3, jh=tid&1;
    float4 acc = make_float4(0.f,0.f,0.f,0.f);
    for (int j=jh*64; j<jh*64+64; j++){
      float p = Ls[q2][j];
      float4 v = *(float4*)&Vs[j][dg*4];
      acc.x += p*v.x; acc.y += p*v.y; acc.z += p*v.z; acc.w += p*v.w;
    }
    acc.x += __shfl_xor(acc.x,1); acc.y += __shfl_xor(acc.y,1);
    acc.z += __shfl_xor(acc.z,1); acc.w += __shfl_xor(acc.w,1);
    if (jh==0){
      long long mrow = (long long)(s*NATOM + qb*32 + q2);
      float inv = 1.0f / rowv[q2];
      us4 gt = *(const us4*)&qkvg[mrow*512 + 384 + h*16 + dg*4];
      us4 st;
      st[0] = f2b(sigm(b2f(gt[0]))*acc.x*inv);
      st[1] = f2b(sigm(b2f(gt[1]))*acc.y*inv);
      st[2] = f2b(sigm(b2f(gt[2]))*acc.z*inv);
      st[3] = f2b(sigm(b2f(gt[3]))*acc.w*inv);
      *(us4*)(og + mrow*128 + h*16 + dg*4) = st;
    }
  }
}

// MFMA GEMM with fused A-staging. BM = rows per block (64 or 32), 64 cols per block.
// AM: 0 = A bf16 [M][K]; 1 = adaptive-LN of f32 A[M][128] with snp p1 (bf16 gate/shift);
//     2 = silu(hp[c])*hp[256+c] from bf16 [M][512], K=256; 3 = f32->bf16 cast [M][128];
//     4 = LN(atom_proj)*w+b (f32 w,b per z from p1..p4), M=2048.
// C-modes: 0 store f32, 1 relu f32, 2 f32 C += sigmoid(bf16 gate)*acc,
//          3 store bf16, 4 relu bf16
template<int AM, int BM>
__global__ __launch_bounds__(256) void gemm_f(
    const void* __restrict__ Asrc, long long strideA,
    const ushortx* __restrict__ B, long long strideB,
    const float* __restrict__ bias, long long strideBias,
    void* Cv, long long strideC,
    int M, int N, int K, int mode,
    const ushortx* __restrict__ gate, int gate_ld, int gate_coloff,
    const void* __restrict__ p1, const void* __restrict__ p2,
    const void* __restrict__ p3, const void* __restrict__ p4)
{
  constexpr int CG  = 256/BM;   // threads per row for A staging
  constexpr int XC  = 128/CG;   // A elems per thread per 128-k chunk
  constexpr int F4  = XC/8;     // bf16-float4 groups per thread
  constexpr int ACI = BM/32;    // acc row-tiles per wave
  int z = blockIdx.z;
  B += z*strideB;
  if (bias) bias += z*strideBias;
  float* C = (float*)Cv + z*strideC;
  ushortx* Cu = (ushortx*)Cv + z*strideC;
  __shared__ ushortx At[BM][136];
  __shared__ ushortx Bt[64][136];
  int tid = threadIdx.x;
  int rowBase = blockIdx.y*BM, colBase = blockIdx.x*64;
  int wave = tid>>6, lane = tid&63;
  int wr = (wave>>1)*(BM/2), wc = (wave&1)*32;
  int lr = lane&15, lk = (lane>>4)*8;
  f32x4 acc[ACI][2];
  #pragma unroll
  for (int i=0;i<ACI;i++)
    #pragma unroll
    for (int j=0;j<2;j++) acc[i][j] = (f32x4){0.f,0.f,0.f,0.f};

  int sr = tid/CG, q = tid%CG, cs = q*XC;
  int row = rowBase + sr;
  int bsr = tid>>2, bq = tid&3, bcs = bq*32;

  for (int kc=0; kc<K; kc+=128){
    if (kc) __syncthreads();
    // ---- stage A ----
    if (AM==0){
      const ushortx* Ab = (const ushortx*)Asrc + z*strideA;
      const float4* ag = (const float4*)(Ab + (long long)row*K + kc + cs);
      #pragma unroll
      for (int u=0;u<F4;u++) *(float4*)&At[sr][cs+u*8] = ag[u];
    } else if (AM==3){
      const float* Af_ = (const float*)Asrc;
      const float4* ar = (const float4*)(Af_ + (long long)row*128 + cs);
      #pragma unroll
      for (int u=0;u<F4;u++){
        float4 a = ar[2*u], b = ar[2*u+1];
        U8 pk;
        pk.u[0]=f2b(a.x); pk.u[1]=f2b(a.y); pk.u[2]=f2b(a.z); pk.u[3]=f2b(a.w);
        pk.u[4]=f2b(b.x); pk.u[5]=f2b(b.y); pk.u[6]=f2b(b.z); pk.u[7]=f2b(b.w);
        *(float4*)&At[sr][cs+u*8] = pk.v;
      }
    } else if (AM==2){
      const ushortx* hp = (const ushortx*)Asrc;
      const float4* xr = (const float4*)(hp + (long long)row*512 + kc + cs);
      const float4* yr = (const float4*)(hp + (long long)row*512 + 256 + kc + cs);
      #pragma unroll
      for (int u=0;u<F4;u++){
        U8 xa, ya, pk;
        xa.v = xr[u]; ya.v = yr[u];
        #pragma unroll
        for (int t=0;t<8;t++){
          float x = b2f(xa.u[t]), y = b2f(ya.u[t]);
          pk.u[t] = f2b(x*sigm(x)*y);
        }
        *(float4*)&At[sr][cs+u*8] = pk.v;
      }
    } else { // AM==1 or AM==4: LN staging, K=128
      const float* arow = (const float*)Asrc + (long long)row*128;
      float x[XC]; float s=0.f, sq=0.f;
      const float4* ar = (const float4*)(arow + cs);
      #pragma unroll
      for (int u=0;u<XC/4;u++){
        float4 t = ar[u];
        x[4*u]=t.x; x[4*u+1]=t.y; x[4*u+2]=t.z; x[4*u+3]=t.w;
        s += t.x+t.y+t.z+t.w;
        sq += t.x*t.x+t.y*t.y+t.z*t.z+t.w*t.w;
      }
      #pragma unroll
      for (int off=1; off<CG; off<<=1){ s += __shfl_xor(s,off); sq += __shfl_xor(sq,off); }
      float mu = s*(1.f/128.f), var = sq*(1.f/128.f)-mu*mu;
      float rs = rsqrtf(var + 1e-5f);
      if (AM==1){
        const ushortx* sp = (const ushortx*)p1 + (long long)(row & (NATOM-1))*384;
        const float4* gr = (const float4*)(sp + cs);
        const float4* hr = (const float4*)(sp + 128 + cs);
        #pragma unroll
        for (int u=0;u<F4;u++){
          U8 ga, ha, pk;
          ga.v = gr[u]; ha.v = hr[u];
          #pragma unroll
          for (int t=0;t<8;t++)
            pk.u[t] = f2b(sigm(b2f(ga.u[t]))*((x[8*u+t]-mu)*rs) + b2f(ha.u[t]));
          *(float4*)&At[sr][cs+u*8] = pk.v;
        }
      } else { // AM==4
        int iw = z>>1, tw = z&1;
        const float* w = (const float*)(tw?p3:p1) + iw*128;
        const float* b = (const float*)(tw?p4:p2) + iw*128;
        const float4* wrp = (const float4*)(w + cs);
        const float4* brp = (const float4*)(b + cs);
        #pragma unroll
        for (int u=0;u<F4;u++){
          float4 wa = wrp[2*u], wb = wrp[2*u+1];
          float4 ba = brp[2*u], bb = brp[2*u+1];
          U8 pk;
          pk.u[0]=f2b((x[8*u  ]-mu)*rs*wa.x+ba.x);
          pk.u[1]=f2b((x[8*u+1]-mu)*rs*wa.y+ba.y);
          pk.u[2]=f2b((x[8*u+2]-mu)*rs*wa.z+ba.z);
          pk.u[3]=f2b((x[8*u+3]-mu)*rs*wa.w+ba.w);
          pk.u[4]=f2b((x[8*u+4]-mu)*rs*wb.x+bb.x);
          pk.u[5]=f2b((x[8*u+5]-mu)*rs*wb.y+bb.y);
          pk.u[6]=f2b((x[8*u+6]-mu)*rs*wb.z+bb.z);
          pk.u[7]=f2b((x[8*u+7]-mu)*rs*wb.w+bb.w);
          *(float4*)&At[sr][cs+u*8] = pk.v;
        }
      }
    }
    // ---- stage B ----
    {
      const float4* bg = (const float4*)(B + (long long)(colBase+bsr)*K + kc + bcs);
      #pragma unroll
      for (int u=0;u<4;u++) *(float4*)&Bt[bsr][bcs+u*8] = bg[u];
    }
    __syncthreads();
    #pragma unroll
    for (int ks=0; ks<4; ks++){
      bf16x8 b0 = *(const bf16x8*)&Bt[wc+lr][ks*32+lk];
      bf16x8 b1 = *(const bf16x8*)&Bt[wc+16+lr][ks*32+lk];
      #pragma unroll
      for (int i=0;i<ACI;i++){
        bf16x8 a = *(const bf16x8*)&At[wr+i*16+lr][ks*32+lk];
        acc[i][0] = __builtin_amdgcn_mfma_f32_16x16x32_bf16(a,b0,acc[i][0],0,0,0);
        acc[i][1] = __builtin_amdgcn_mfma_f32_16x16x32_bf16(a,b1,acc[i][1],0,0,0);
      }
    }
  }
  int crow0 = rowBase + wr + (lane>>4)*4;
  int ccol0 = colBase + wc + lr;
  #pragma unroll
  for (int i=0;i<ACI;i++){
    #pragma unroll
    for (int j=0;j<2;j++){
      int col = ccol0 + j*16;
      float bv = bias ? bias[col] : 0.f;
      #pragma unroll
      for (int rr=0; rr<4; rr++){
        int rrow = crow0 + i*16 + rr;
        float v = acc[i][j][rr] + bv;
        long long ci = (long long)rrow*N + col;
        if (mode==1) C[ci] = fmaxf(v, 0.f);
        else if (mode==2){
          int n = rrow & (NATOM-1);
          C[ci] += sigm(b2f(gate[(long long)n*gate_ld + gate_coloff + col])) * v;
        } else if (mode==3) Cu[ci] = f2b(v);
        else if (mode==4) Cu[ci] = f2b(fmaxf(v, 0.f));
        else C[ci] = v;
      }
    }
  }
}

__global__ __launch_bounds__(128) void tokagg_kernel(const int* __restrict__ tok_idx,
    const float* __restrict__ qtok, float* __restrict__ out)
{
  int t = blockIdx.x;
  int lo=0, hi=NATOM;
  while (lo<hi){ int mid=(lo+hi)>>1; if (tok_idx[mid] < t) lo=mid+1; else hi=mid; }
  int start = lo;
  lo = start; hi = NATOM;
  while (lo<hi){ int mid=(lo+hi)>>1; if (tok_idx[mid] <= t) lo=mid+1; else hi=mid; }
  int end = lo;
  int cnt = end - start;
  float inv = 1.0f / (float)(cnt>0 ? cnt : 1);
  for (int s=0; s<SD; s++)
    for (int c=threadIdx.x; c<CTD; c+=128){
      float acc = 0.f;
      for (int n=start; n<end; n++) acc += qtok[((long long)(s*NATOM+n))*CTD + c];
      out[(long long)(s*TT + t)*CTD + c] = acc*inv;
    }
}

extern "C" void kernel_launch(void* const* d_in, const int* in_sizes, int n_in,
                              void* d_out, int out_size, void* d_ws, size_t ws_size,
                              hipStream_t stream)
{
  const float* atom_single = (const float*)d_in[0];
  const float* atom_proj   = (const float*)d_in[1];
  const float* atom_pair   = (const float*)d_in[2];
  const float* mask        = (const float*)d_in[3];
  const int*   tok_idx     = (const int*)  d_in[4];
  const float* aln_s_w     = (const float*)d_in[5];
  const float* aln_s_b     = (const float*)d_in[6];
  const float* pair_ln_w   = (const float*)d_in[14];
  const float* pair_ln_b   = (const float*)d_in[15];
  const float* pair_w      = (const float*)d_in[16];
  const float* t_aln_s_w   = (const float*)d_in[21];
  const float* t_aln_s_b   = (const float*)d_in[22];

  char* wsb = (char*)d_ws;
  ushortx* W3T    = (ushortx*)(wsb+OFFB_W3T);
  float*   B3     = (float*)  (wsb+OFFB_B3);
  ushortx* WQKVGT = (ushortx*)(wsb+OFFB_WQKVGT);
  float*   BQ     = (float*)  (wsb+OFFB_BQ);
  ushortx* WOUTT  = (ushortx*)(wsb+OFFB_WOUTT);
  ushortx* WABT   = (ushortx*)(wsb+OFFB_WABT);
  ushortx* WTOUTT = (ushortx*)(wsb+OFFB_WTOUTT);
  ushortx* WTOKT  = (ushortx*)(wsb+OFFB_WTOKT);
  ushortx* A1     = (ushortx*)(wsb+OFFB_A1);
  ushortx* SNP    = (ushortx*)(wsb+OFFB_SNP);
  float*   Af     = (float*)  (wsb+OFFB_A);
  ushortx* QKVG   = (ushortx*)(wsb+OFFB_QKVG);
  ushortx* ZB     = (ushortx*)(wsb+OFFB_ZB);
  float*   QTOK   = (float*)  (wsb+OFFB_QTOK);

  WPtrs P;
  P.aln_gate_w=(const float*)d_in[7];  P.aln_gate_b=(const float*)d_in[8];  P.aln_shift_w=(const float*)d_in[9];
  P.og_w=(const float*)d_in[19]; P.og_b=(const float*)d_in[20];
  P.t_aln_gate_w=(const float*)d_in[23]; P.t_aln_gate_b=(const float*)d_in[24]; P.t_aln_shift_w=(const float*)d_in[25];
  P.t_og_w=(const float*)d_in[29]; P.t_og_b=(const float*)d_in[30];
  P.q_w=(const float*)d_in[10]; P.q_b=(const float*)d_in[11]; P.k_w=(const float*)d_in[12];
  P.v_w=(const float*)d_in[13]; P.gate_w=(const float*)d_in[17]; P.out_w=(const float*)d_in[18];
  P.t_a_w=(const float*)d_in[26]; P.t_b_w=(const float*)d_in[27]; P.t_out_w=(const float*)d_in[28];
  P.tok_w=(const float*)d_in[31];

  // prologue: pack (3471) + copy (2048) + zb (1024) in one launch
  prologue_kernel<<<6543,256,0,stream>>>(P, wsb, atom_single, atom_pair,
      pair_ln_w, pair_ln_b, pair_w);
  // snp[which] = (LN(atom_proj)*w_which+b_which) @ W3[which]^T + b3[which]  -> bf16
  gemm_f<4,64><<<dim3(6,32,6),256,0,stream>>>(atom_proj, 0, W3T, 49152ll,
      B3, 384ll, SNP, 786432ll, NATOM, 384, 128, 3, nullptr, 0, 0,
      aln_s_w, aln_s_b, t_aln_s_w, t_aln_s_b);

  for (int i=0;i<NBI;i++){
    const ushortx* snpA = SNP + (long long)(2*i)*786432;
    const ushortx* snpT = SNP + (long long)(2*i+1)*786432;
    // qkvg = modln(a) @ [q|k|v|gate] (+[q_b|0|0|0])  -> bf16
    gemm_f<1,64><<<dim3(8,64,1),256,0,stream>>>(Af, 0, WQKVGT + (long long)i*65536, 0,
        BQ + (long long)i*512, 0, QKVG, 0, MR, 512, 128, 3, nullptr, 0, 0,
        snpA, nullptr, nullptr, nullptr);
    attn_kernel<<<dim3(64,8,2),256,0,stream>>>(QKVG, ZB + (long long)i*2097152, mask, A1);
    // a += sigmoid(og_pre) * (og @ out_w)   (BM=32 -> 256 blocks)
    gemm_f<0,32><<<dim3(2,128,1),256,0,stream>>>(A1, 0, WOUTT + (long long)i*16384, 0,
        nullptr, 0, Af, 0, MR, 128, 128, 2, snpA, 384, 256,
        nullptr, nullptr, nullptr, nullptr);
    // hidden_pre = modln(a) @ [t_a|t_b]  -> bf16
    gemm_f<1,64><<<dim3(8,64,1),256,0,stream>>>(Af, 0, WABT + (long long)i*65536, 0,
        nullptr, 0, QKVG, 0, MR, 512, 128, 3, nullptr, 0, 0,
        snpT, nullptr, nullptr, nullptr);
    // a += sigmoid(t_og_pre) * (silu(h_a)*h_b @ t_out_w)   (BM=32 -> 256 blocks)
    gemm_f<2,32><<<dim3(2,128,1),256,0,stream>>>(QKVG, 0, WTOUTT + (long long)i*32768, 0,
        nullptr, 0, Af, 0, MR, 128, 256, 2, snpT, 384, 256,
        nullptr, nullptr, nullptr, nullptr);
  }
  // q_tok = relu(a @ tok_w)  (keep f32: closest to output)
  gemm_f<3,64><<<dim3(6,64,1),256,0,stream>>>(Af, 0, WTOKT, 0, nullptr, 0,
      QTOK, 0, MR, CTD, 128, 1, nullptr, 0, 0,
      nullptr, nullptr, nullptr, nullptr);
  tokagg_kernel<<<TT,128,0,stream>>>(tok_idx, QTOK, (float*)d_out);
}

// Round 2
// 533.800 us; speedup vs baseline: 1.1952x; 1.1258x over previous
//
#include <hip/hip_runtime.h>
#include <math.h>

#define NATOM 2048
#define CD 128
#define SD 2
#define TT 512
#define CTD 384
#define NBI 3
#define MR 4096  // SD*NATOM

typedef unsigned short ushortx;
typedef __attribute__((ext_vector_type(8))) short bf16x8;
typedef __attribute__((ext_vector_type(4))) float f32x4;
typedef __attribute__((ext_vector_type(4))) unsigned short us4;

__device__ __forceinline__ float sigm(float x){ return 1.0f/(1.0f+expf(-x)); }
__device__ __forceinline__ ushortx f2b(float f){
  union { float f; unsigned u; } v; v.f = f;
  unsigned r = v.u + 0x7fffu + ((v.u>>16)&1u);
  return (ushortx)(r>>16);
}
__device__ __forceinline__ float b2f(ushortx u){
  union { unsigned u; float f; } v; v.u = ((unsigned)u)<<16; return v.f;
}
union U8 { ushortx u[8]; float4 v; };

__device__ __forceinline__ void unpack8(float* dst, float4 v){
  U8 pk; pk.v = v;
  #pragma unroll
  for (int t=0;t<8;t++) dst[t] = b2f(pk.u[t]);
}

// ---- workspace layout (byte offsets, 256-aligned) ----
#define OFFB_W3T    0ll        // ushort 6*384*128   [n][k] [gate|shift|og]
#define OFFB_B3     589824ll   // f32 6*384
#define OFFB_WQKVGT 599040ll   // ushort 3*512*128
#define OFFB_BQ     992256ll   // f32 3*512
#define OFFB_WOUTT  998400ll   // ushort 3*128*128
#define OFFB_WABT   1096704ll  // ushort 3*512*128
#define OFFB_WTOUTT 1489920ll  // ushort 3*128*256
#define OFFB_WTOKT  1686528ll  // ushort 384*128
#define OFFB_A1     1784832ll  // ushort 4096*128 (attention og output)
#define OFFB_SNP    2833408ll  // ushort 6*2048*384 (bf16)
#define OFFB_A      12270592ll // f32 4096*128
#define OFFB_QKVG   14367744ll // ushort 4096*512 (bf16)
#define OFFB_ZB     18562048ll // ushort 3*8*2048*128 (bf16)
#define OFFB_QTOK   31144960ll // f32 4096*384

struct WPtrs {
  const float *aln_gate_w, *aln_gate_b, *aln_shift_w, *og_w, *og_b;
  const float *t_aln_gate_w, *t_aln_gate_b, *t_aln_shift_w, *t_og_w, *t_og_b;
  const float *q_w, *q_b, *k_w, *v_w, *gate_w, *out_w;
  const float *t_a_w, *t_b_w, *t_out_w, *tok_w;
};

// merged prologue: weight pack (blocks 0..3470) + atom_single copy (3471..5518)
// + zb compute (5519..6542). All independent of each other.
__global__ __launch_bounds__(256) void prologue_kernel(WPtrs P, char* __restrict__ wsb,
  const float* __restrict__ atom_single, const float* __restrict__ atom_pair,
  const float* __restrict__ plw, const float* __restrict__ plb, const float* __restrict__ pw)
{
  int b = blockIdx.x;
  if (b < 3471){
    long long idx = (long long)b*256 + threadIdx.x;
    const long long s0=294912, s1=2304, s2=196608, s3=1536, s4=49152, s5=196608, s6=98304;
    if (idx < s0) { // W3T[which][n][k]
      int which = (int)(idx/49152); int r = (int)(idx%49152); int n=r/128, k=r%128;
      int i = which>>1, t = which&1;
      const float* src;
      if (n<128)      src = (t?P.t_aln_gate_w :P.aln_gate_w ) + i*16384 + k*128 + n;
      else if (n<256) src = (t?P.t_aln_shift_w:P.aln_shift_w) + i*16384 + k*128 + (n-128);
      else            src = (t?P.t_og_w       :P.og_w       ) + i*16384 + k*128 + (n-256);
      ((ushortx*)(wsb+OFFB_W3T))[idx] = f2b(*src); return;
    }
    idx -= s0;
    if (idx < s1) {
      int which = (int)(idx/384); int col = (int)(idx%384); int i=which>>1, t=which&1;
      float v = 0.f;
      if (col<128)       v = (t?P.t_aln_gate_b:P.aln_gate_b)[i*128+col];
      else if (col>=256) v = (t?P.t_og_b      :P.og_b      )[i*128+col-256];
      ((float*)(wsb+OFFB_B3))[idx] = v; return;
    }
    idx -= s1;
    if (idx < s2) { // WQKVGT[i][n][k]
      int i = (int)(idx/65536); int r = (int)(idx%65536); int n=r/128, k=r%128;
      int seg = n>>7, c = n&127;
      const float* src = (seg==0?P.q_w: seg==1?P.k_w: seg==2?P.v_w: P.gate_w) + i*16384 + k*128 + c;
      ((ushortx*)(wsb+OFFB_WQKVGT))[idx] = f2b(*src); return;
    }
    idx -= s2;
    if (idx < s3) {
      int i = (int)(idx/512); int col = (int)(idx%512);
      ((float*)(wsb+OFFB_BQ))[idx] = (col<128) ? P.q_b[i*128+col] : 0.f; return;
    }
    idx -= s3;
    if (idx < s4) { // WOUTT
      int i = (int)(idx/16384); int r = (int)(idx%16384); int n=r/128, k=r%128;
      ((ushortx*)(wsb+OFFB_WOUTT))[idx] = f2b(P.out_w[i*16384 + k*128 + n]); return;
    }
    idx -= s4;
    if (idx < s5) { // WABT
      int i = (int)(idx/65536); int r = (int)(idx%65536); int n=r/128, k=r%128;
      const float* src = (n<256) ? P.t_a_w + i*32768 + k*256 + n
                                 : P.t_b_w + i*32768 + k*256 + (n-256);
      ((ushortx*)(wsb+OFFB_WABT))[idx] = f2b(*src); return;
    }
    idx -= s5;
    if (idx < s6) { // WTOUTT
      int i = (int)(idx/32768); int r = (int)(idx%32768); int n=r/256, k=r%256;
      ((ushortx*)(wsb+OFFB_WTOUTT))[idx] = f2b(P.t_out_w[i*32768 + k*128 + n]); return;
    }
    idx -= s6;
    { // WTOKT
      int n = (int)(idx/128); int k = (int)(idx%128);
      ((ushortx*)(wsb+OFFB_WTOKT))[idx] = f2b(P.tok_w[k*384 + n]); return;
    }
  }
  if (b < 5519){
    int i = (b-3471)*256 + threadIdx.x;
    ((float*)(wsb+OFFB_A))[i] = atom_single[i];
    return;
  }
  // zb part: zb_all[it][h][q][j] bf16, j in [0,128): key m = (q&~31)-48+j
  {
    int idx = (b-5519)*256 + threadIdx.x;
    int q = idx>>7, j = idx&127;
    int m = (q & ~31) - 48 + j;
    bool ok = (m>=0 && m<NATOM);
    float x[16]; float mu=0.f, rs=0.f;
    if (ok){
      float s=0.f, sq=0.f;
      const float* p = atom_pair + ((long long)q*NATOM + m)*16;
      #pragma unroll
      for (int c=0;c<16;c++){ x[c]=p[c]; s+=x[c]; sq+=x[c]*x[c]; }
      mu = s*(1.f/16.f); float var = sq*(1.f/16.f)-mu*mu; rs = rsqrtf(var+1e-5f);
    }
    ushortx* zb = (ushortx*)(wsb+OFFB_ZB);
    #pragma unroll
    for (int it=0; it<NBI; it++){
      float out[8] = {0,0,0,0,0,0,0,0};
      if (ok){
        #pragma unroll
        for (int c=0;c<16;c++){
          float xn = (x[c]-mu)*rs*plw[it*16+c] + plb[it*16+c];
          #pragma unroll
          for (int h=0;h<8;h++) out[h] += xn * pw[it*128 + c*8 + h];
        }
      }
      #pragma unroll
      for (int h=0;h<8;h++)
        zb[(((long long)it*8+h)*NATOM + q)*128 + j] = f2b(out[h]);
    }
  }
}

// banded attention + fused output gate; qkvg and zb are bf16; K/V kept bf16 in LDS
__global__ __launch_bounds__(256) void attn_kernel(const ushortx* __restrict__ qkvg,
  const ushortx* __restrict__ zb, const float* __restrict__ mask, ushortx* __restrict__ og)
{
  int qb = blockIdx.x, h = blockIdx.y, s = blockIdx.z;
  int base = qb*32 - 48;
  __shared__ __align__(16) float Qs[32][20];
  __shared__ __align__(16) ushortx KsU[128][24];
  __shared__ __align__(16) ushortx VsU[128][24];
  __shared__ __align__(16) float Ls[32][132];
  __shared__ float maskb[128], redx[32][8], rowv[32];
  int tid = threadIdx.x;
  for (int idx=tid; idx<32*2; idx+=256){
    int r=idx>>1, d8=(idx&1)*8;
    float4 v = *(const float4*)&qkvg[((long long)(s*NATOM + qb*32 + r))*512 + h*16 + d8];
    unpack8(&Qs[r][d8], v);
  }
  for (int idx=tid; idx<512; idx+=256){
    int j = idx&127, d8 = ((idx>>7)&1)*8, kv = idx>>8;
    int m = base + j; int mc = m<0?0:(m>NATOM-1?NATOM-1:m);
    long long row = ((long long)(s*NATOM + mc))*512;
    float4 v = *(const float4*)&qkvg[row + (kv?256:128) + h*16 + d8];
    if (kv) *(float4*)&VsU[j][d8] = v; else *(float4*)&KsU[j][d8] = v;
  }
  if (tid < 128){
    int m = base + tid;
    maskb[tid] = (m>=0 && m<NATOM) ? (mask[m]-1.0f)*1e8f : -1e30f;
  }
  __syncthreads();
  int r = tid>>3, g = tid&7;
  {
    float4 q0=*(float4*)&Qs[r][0], q1=*(float4*)&Qs[r][4], q2=*(float4*)&Qs[r][8], q3=*(float4*)&Qs[r][12];
    const ushortx* zrow = zb + ((long long)h*NATOM + (qb*32+r))*128;
    #pragma unroll
    for (int j=g; j<128; j+=8){
      U8 ka, kb; ka.v = *(const float4*)&KsU[j][0]; kb.v = *(const float4*)&KsU[j][8];
      float dot = q0.x*b2f(ka.u[0]) + q0.y*b2f(ka.u[1]) + q0.z*b2f(ka.u[2]) + q0.w*b2f(ka.u[3])
                + q1.x*b2f(ka.u[4]) + q1.y*b2f(ka.u[5]) + q1.z*b2f(ka.u[6]) + q1.w*b2f(ka.u[7])
                + q2.x*b2f(kb.u[0]) + q2.y*b2f(kb.u[1]) + q2.z*b2f(kb.u[2]) + q2.w*b2f(kb.u[3])
                + q3.x*b2f(kb.u[4]) + q3.y*b2f(kb.u[5]) + q3.z*b2f(kb.u[6]) + q3.w*b2f(kb.u[7]);
      Ls[r][j] = dot*0.25f + b2f(zrow[j]) + maskb[j];
    }
  }
  __syncthreads();
  float pmax = -1e30f;
  for (int j=g*16; j<g*16+16; j++) pmax = fmaxf(pmax, Ls[r][j]);
  redx[r][g] = pmax; __syncthreads();
  if (g==0){ float mx=redx[r][0]; for(int u=1;u<8;u++) mx=fmaxf(mx,redx[r][u]); rowv[r]=mx; }
  __syncthreads();
  float mx = rowv[r];
  float psum = 0.f;
  for (int j=g*16; j<g*16+16; j++){ float e = expf(Ls[r][j]-mx); Ls[r][j]=e; psum += e; }
  redx[r][g] = psum; __syncthreads();
  if (g==0){ float sm=0.f; for(int u=0;u<8;u++) sm+=redx[r][u]; rowv[r]=sm; }
  __syncthreads();
  {
    int q2=tid>>3, dg=(tid>>1)&3, jh=tid&1;
    float4 acc = make_float4(0.f,0.f,0.f,0.f);
    for (int j=jh*64; j<jh*64+64; j++){
      float p = Ls[q2][j];
      us4 vv = *(const us4*)&VsU[j][dg*4];
      acc.x += p*b2f(vv[0]); acc.y += p*b2f(vv[1]);
      acc.z += p*b2f(vv[2]); acc.w += p*b2f(vv[3]);
    }
    acc.x += __shfl_xor(acc.x,1); acc.y += __shfl_xor(acc.y,1);
    acc.z += __shfl_xor(acc.z,1); acc.w += __shfl_xor(acc.w,1);
    if (jh==0){
      long long mrow = (long long)(s*NATOM + qb*32 + q2);
      float inv = 1.0f / rowv[q2];
      us4 gt = *(const us4*)&qkvg[mrow*512 + 384 + h*16 + dg*4];
      us4 st;
      st[0] = f2b(sigm(b2f(gt[0]))*acc.x*inv);
      st[1] = f2b(sigm(b2f(gt[1]))*acc.y*inv);
      st[2] = f2b(sigm(b2f(gt[2]))*acc.z*inv);
      st[3] = f2b(sigm(b2f(gt[3]))*acc.w*inv);
      *(us4*)(og + mrow*128 + h*16 + dg*4) = st;
    }
  }
}

// Fused post-attention chain, row-local (16 rows/block, 256 blocks):
//   Af += sigm(ogA)*(A1 @ Wout)                 [passes 0..1]
//   a2 = modln_T(Af); h = a2 @ Wab              [passes 2..9; hidden stays in LDS]
//   Af += sigm(ogT)*(silu(h_a)*h_b @ Wtout)     [passes 10..13, K=256]
//   write Af; LAST? qtok=relu(Af@Wtok) : qkvg_next = modln_Anext(Af)@Wqkvg+bq
//                                               [passes 14..NP)
template<int LAST>
__global__ __launch_bounds__(256) void postattn_kernel(
  float* __restrict__ Af, const ushortx* __restrict__ A1,
  const ushortx* __restrict__ Wout,   // [128][128]
  const ushortx* __restrict__ Wab,    // [512][128]
  const ushortx* __restrict__ Wtout,  // [128][256]
  const ushortx* __restrict__ WN,     // qkvg_next [512][128] | tok [384][128]
  const float*   __restrict__ biasN,  // [512] (null if LAST)
  const ushortx* __restrict__ snpA,   // this iter A-side [2048][384]
  const ushortx* __restrict__ snpT,   // this iter T-side
  const ushortx* __restrict__ snpN,   // next iter A-side (null if LAST)
  ushortx* __restrict__ QKVG,         // out (non-last)
  float*   __restrict__ QTOK)         // out (last)
{
  __shared__ __align__(16) ushortx Bt[2][64][136];
  __shared__ __align__(16) float   Afr[16][132];
  __shared__ __align__(16) ushortx A2t[16][136];
  __shared__ __align__(16) ushortx Ht[16][264];   // raw h_a (bf16)
  __shared__ __align__(16) ushortx XX[16*264];    // A1t (p<2) then Hs (p>=6)
  ushortx (*A1t)[136] = (ushortx(*)[136])XX;
  ushortx (*Hs)[264]  = (ushortx(*)[264])XX;

  int tid=threadIdx.x, rowBase=blockIdx.x*16;
  int wave=tid>>6, lane=tid&63, lr=lane&15, lk=(lane>>4)*8;
  int wc = wave*16;
  int r=tid>>4, c8=(tid&15)*8;
  long long grow = rowBase + r;
  int sr=tid>>2, csB=(tid&3)*32;
  int crow = (lane>>4)*4;

  // stage A1 rows + Af rows
  *(float4*)&A1t[r][c8] = *(const float4*)&A1[grow*128 + c8];
  { const float4* ap=(const float4*)&Af[grow*128+c8];
    *(float4*)&Afr[r][c8]=ap[0]; *(float4*)&Afr[r][c8+4]=ap[1]; }
  const int NP = LAST ? 20 : 22;
  // stage pass 0 (Wout, first 64 cols)
  {
    const float4* bg = (const float4*)(Wout + (long long)sr*128 + csB);
    #pragma unroll
    for (int u=0;u<4;u++) *(float4*)&Bt[0][sr][csB+u*8] = bg[u];
  }
  f32x4 acc = (f32x4){0.f,0.f,0.f,0.f};
  for (int p=0; p<NP; p++){
    __syncthreads();
    // prefetch next pass's B tile into the other buffer
    if (p+1 < NP){
      int pn = p+1;
      const ushortx* bsrc; long long bstride;
      if (pn<2)      { bsrc = Wout  + (long long)(pn*64)*128;                      bstride=128; }
      else if (pn<10){ bsrc = Wab   + (long long)((pn-2)*64)*128;                  bstride=128; }
      else if (pn<14){ int q=pn-10; bsrc = Wtout + (long long)((q>>1)*64)*256 + (q&1)*128; bstride=256; }
      else           { int q=pn-14; bsrc = WN    + (long long)(q*64)*128;          bstride=128; }
      const float4* bg=(const float4*)(bsrc + (long long)sr*bstride + csB);
      #pragma unroll
      for (int u=0;u<4;u++) *(float4*)&Bt[pn&1][sr][csB+u*8] = bg[u];
    }
    // pre-MFMA transforms (uniform branches; internal barrier is uniform)
    if (p==2){
      float x[8], s=0.f, sq=0.f;
      #pragma unroll
      for (int u=0;u<8;u++){ x[u]=Afr[r][c8+u]; s+=x[u]; sq+=x[u]*x[u]; }
      #pragma unroll
      for (int off=1; off<16; off<<=1){ s+=__shfl_xor(s,off); sq+=__shfl_xor(sq,off); }
      float mu=s*(1.f/128.f), rs=rsqrtf(sq*(1.f/128.f)-mu*mu+1e-5f);
      const ushortx* sp = snpT + (long long)(grow&2047)*384;
      U8 ga,ha,pk; ga.v=*(const float4*)&sp[c8]; ha.v=*(const float4*)&sp[128+c8];
      #pragma unroll
      for (int t=0;t<8;t++) pk.u[t]=f2b(sigm(b2f(ga.u[t]))*((x[t]-mu)*rs)+b2f(ha.u[t]));
      *(float4*)&A2t[r][c8]=pk.v;
      __syncthreads();
    }
    if (p==14){
      float x[8], s=0.f, sq=0.f;
      #pragma unroll
      for (int u=0;u<8;u++){ x[u]=Afr[r][c8+u]; s+=x[u]; sq+=x[u]*x[u]; }
      { float4* ap=(float4*)&Af[grow*128+c8];
        ap[0]=*(float4*)&Afr[r][c8]; ap[1]=*(float4*)&Afr[r][c8+4]; }
      if (LAST){
        U8 pk;
        #pragma unroll
        for (int t=0;t<8;t++) pk.u[t]=f2b(x[t]);
        *(float4*)&A2t[r][c8]=pk.v;
      } else {
        #pragma unroll
        for (int off=1; off<16; off<<=1){ s+=__shfl_xor(s,off); sq+=__shfl_xor(sq,off); }
        float mu=s*(1.f/128.f), rs=rsqrtf(sq*(1.f/128.f)-mu*mu+1e-5f);
        const ushortx* sp = snpN + (long long)(grow&2047)*384;
        U8 ga,ha,pk; ga.v=*(const float4*)&sp[c8]; ha.v=*(const float4*)&sp[128+c8];
        #pragma unroll
        for (int t=0;t<8;t++) pk.u[t]=f2b(sigm(b2f(ga.u[t]))*((x[t]-mu)*rs)+b2f(ha.u[t]));
        *(float4*)&A2t[r][c8]=pk.v;
      }
      __syncthreads();
    }
    // MFMA (acc carries across tout k-halves: reset except at p==11,13)
    if (p!=11 && p!=13) acc=(f32x4){0.f,0.f,0.f,0.f};
    #pragma unroll
    for (int ks=0; ks<4; ks++){
      bf16x8 a;
      if (p<2)       a = *(const bf16x8*)&A1t[lr][ks*32+lk];
      else if (p<10) a = *(const bf16x8*)&A2t[lr][ks*32+lk];
      else if (p<14){ int kc=(p-10)&1; a = *(const bf16x8*)&Hs[lr][kc*128+ks*32+lk]; }
      else           a = *(const bf16x8*)&A2t[lr][ks*32+lk];
      bf16x8 b = *(const bf16x8*)&Bt[p&1][wc+lr][ks*32+lk];
      acc = __builtin_amdgcn_mfma_f32_16x16x32_bf16(a,b,acc,0,0,0);
    }
    // epilogues
    if (p<2){
      int ccol = p*64 + wc + lr;
      #pragma unroll
      for (int rr=0;rr<4;rr++){
        int rrow=crow+rr;
        float g=b2f(snpA[(long long)((rowBase+rrow)&2047)*384 + 256 + ccol]);
        Afr[rrow][ccol]+=sigm(g)*acc[rr];
      }
    } else if (p<10){
      int cp=p-2; int ccol=cp*64+wc+lr;
      if (cp<4){
        #pragma unroll
        for (int rr=0;rr<4;rr++) Ht[crow+rr][ccol]=f2b(acc[rr]);
      } else {
        int hc=ccol-256;
        #pragma unroll
        for (int rr=0;rr<4;rr++){
          float ha=b2f(Ht[crow+rr][hc]);
          Hs[crow+rr][hc]=f2b(ha*sigm(ha)*acc[rr]);
        }
      }
    } else if (p==11 || p==13){
      int cp=(p-10)>>1; int ccol=cp*64+wc+lr;
      #pragma unroll
      for (int rr=0;rr<4;rr++){
        int rrow=crow+rr;
        float g=b2f(snpT[(long long)((rowBase+rrow)&2047)*384 + 256 + ccol]);
        Afr[rrow][ccol]+=sigm(g)*acc[rr];
      }
    } else if (p>=14){
      int q=p-14; int ccol=q*64+wc+lr;
      if (LAST){
        #pragma unroll
        for (int rr=0;rr<4;rr++)
          QTOK[(long long)(rowBase+crow+rr)*384 + ccol]=fmaxf(acc[rr],0.f);
      } else {
        float bv=biasN[ccol];
        #pragma unroll
        for (int rr=0;rr<4;rr++)
          QKVG[(long long)(rowBase+crow+rr)*512 + ccol]=f2b(acc[rr]+bv);
      }
    }
  }
}

// MFMA GEMM with fused A-staging (used for SNP production and qkvg0).
template<int AM, int BM>
__global__ __launch_bounds__(256) void gemm_f(
    const void* __restrict__ Asrc, long long strideA,
    const ushortx* __restrict__ B, long long strideB,
    const float* __restrict__ bias, long long strideBias,
    void* Cv, long long strideC,
    int M, int N, int K, int mode,
    const ushortx* __restrict__ gate, int gate_ld, int gate_coloff,
    const void* __restrict__ p1, const void* __restrict__ p2,
    const void* __restrict__ p3, const void* __restrict__ p4)
{
  constexpr int CG  = 256/BM;
  constexpr int XC  = 128/CG;
  constexpr int F4  = XC/8;
  constexpr int ACI = BM/32;
  int z = blockIdx.z;
  B += z*strideB;
  if (bias) bias += z*strideBias;
  float* C = (float*)Cv + z*strideC;
  ushortx* Cu = (ushortx*)Cv + z*strideC;
  __shared__ __align__(16) ushortx At[BM][136];
  __shared__ __align__(16) ushortx Bt[64][136];
  int tid = threadIdx.x;
  int rowBase = blockIdx.y*BM, colBase = blockIdx.x*64;
  int wave = tid>>6, lane = tid&63;
  int wr = (wave>>1)*(BM/2), wc = (wave&1)*32;
  int lr = lane&15, lk = (lane>>4)*8;
  f32x4 acc[ACI][2];
  #pragma unroll
  for (int i=0;i<ACI;i++)
    #pragma unroll
    for (int j=0;j<2;j++) acc[i][j] = (f32x4){0.f,0.f,0.f,0.f};

  int sr = tid/CG, q = tid%CG, cs = q*XC;
  int row = rowBase + sr;
  int bsr = tid>>2, bq = tid&3, bcs = bq*32;

  for (int kc=0; kc<K; kc+=128){
    if (kc) __syncthreads();
    if (AM==0){
      const ushortx* Ab = (const ushortx*)Asrc + z*strideA;
      const float4* ag = (const float4*)(Ab + (long long)row*K + kc + cs);
      #pragma unroll
      for (int u=0;u<F4;u++) *(float4*)&At[sr][cs+u*8] = ag[u];
    } else if (AM==3){
      const float* Af_ = (const float*)Asrc;
      const float4* ar = (const float4*)(Af_ + (long long)row*128 + cs);
      #pragma unroll
      for (int u=0;u<F4;u++){
        float4 a = ar[2*u], b = ar[2*u+1];
        U8 pk;
        pk.u[0]=f2b(a.x); pk.u[1]=f2b(a.y); pk.u[2]=f2b(a.z); pk.u[3]=f2b(a.w);
        pk.u[4]=f2b(b.x); pk.u[5]=f2b(b.y); pk.u[6]=f2b(b.z); pk.u[7]=f2b(b.w);
        *(float4*)&At[sr][cs+u*8] = pk.v;
      }
    } else { // AM==1 or AM==4: LN staging, K=128
      const float* arow = (const float*)Asrc + (long long)row*128;
      float x[XC]; float s=0.f, sq=0.f;
      const float4* ar = (const float4*)(arow + cs);
      #pragma unroll
      for (int u=0;u<XC/4;u++){
        float4 t = ar[u];
        x[4*u]=t.x; x[4*u+1]=t.y; x[4*u+2]=t.z; x[4*u+3]=t.w;
        s += t.x+t.y+t.z+t.w;
        sq += t.x*t.x+t.y*t.y+t.z*t.z+t.w*t.w;
      }
      #pragma unroll
      for (int off=1; off<CG; off<<=1){ s += __shfl_xor(s,off); sq += __shfl_xor(sq,off); }
      float mu = s*(1.f/128.f), var = sq*(1.f/128.f)-mu*mu;
      float rs = rsqrtf(var + 1e-5f);
      if (AM==1){
        const ushortx* sp = (const ushortx*)p1 + (long long)(row & (NATOM-1))*384;
        const float4* gr = (const float4*)(sp + cs);
        const float4* hr = (const float4*)(sp + 128 + cs);
        #pragma unroll
        for (int u=0;u<F4;u++){
          U8 ga, ha, pk;
          ga.v = gr[u]; ha.v = hr[u];
          #pragma unroll
          for (int t=0;t<8;t++)
            pk.u[t] = f2b(sigm(b2f(ga.u[t]))*((x[8*u+t]-mu)*rs) + b2f(ha.u[t]));
          *(float4*)&At[sr][cs+u*8] = pk.v;
        }
      } else { // AM==4
        int iw = z>>1, tw = z&1;
        const float* w = (const float*)(tw?p3:p1) + iw*128;
        const float* b = (const float*)(tw?p4:p2) + iw*128;
        const float4* wrp = (const float4*)(w + cs);
        const float4* brp = (const float4*)(b + cs);
        #pragma unroll
        for (int u=0;u<F4;u++){
          float4 wa = wrp[2*u], wb = wrp[2*u+1];
          float4 ba = brp[2*u], bb = brp[2*u+1];
          U8 pk;
          pk.u[0]=f2b((x[8*u  ]-mu)*rs*wa.x+ba.x);
          pk.u[1]=f2b((x[8*u+1]-mu)*rs*wa.y+ba.y);
          pk.u[2]=f2b((x[8*u+2]-mu)*rs*wa.z+ba.z);
          pk.u[3]=f2b((x[8*u+3]-mu)*rs*wa.w+ba.w);
          pk.u[4]=f2b((x[8*u+4]-mu)*rs*wb.x+bb.x);
          pk.u[5]=f2b((x[8*u+5]-mu)*rs*wb.y+bb.y);
          pk.u[6]=f2b((x[8*u+6]-mu)*rs*wb.z+bb.z);
          pk.u[7]=f2b((x[8*u+7]-mu)*rs*wb.w+bb.w);
          *(float4*)&At[sr][cs+u*8] = pk.v;
        }
      }
    }
    {
      const float4* bg = (const float4*)(B + (long long)(colBase+bsr)*K + kc + bcs);
      #pragma unroll
      for (int u=0;u<4;u++) *(float4*)&Bt[bsr][bcs+u*8] = bg[u];
    }
    __syncthreads();
    #pragma unroll
    for (int ks=0; ks<4; ks++){
      bf16x8 b0 = *(const bf16x8*)&Bt[wc+lr][ks*32+lk];
      bf16x8 b1 = *(const bf16x8*)&Bt[wc+16+lr][ks*32+lk];
      #pragma unroll
      for (int i=0;i<ACI;i++){
        bf16x8 a = *(const bf16x8*)&At[wr+i*16+lr][ks*32+lk];
        acc[i][0] = __builtin_amdgcn_mfma_f32_16x16x32_bf16(a,b0,acc[i][0],0,0,0);
        acc[i][1] = __builtin_amdgcn_mfma_f32_16x16x32_bf16(a,b1,acc[i][1],0,0,0);
      }
    }
  }
  int crow0 = rowBase + wr + (lane>>4)*4;
  int ccol0 = colBase + wc + lr;
  #pragma unroll
  for (int i=0;i<ACI;i++){
    #pragma unroll
    for (int j=0;j<2;j++){
      int col = ccol0 + j*16;
      float bv = bias ? bias[col] : 0.f;
      #pragma unroll
      for (int rr=0; rr<4; rr++){
        int rrow = crow0 + i*16 + rr;
        float v = acc[i][j][rr] + bv;
        long long ci = (long long)rrow*N + col;
        if (mode==1) C[ci] = fmaxf(v, 0.f);
        else if (mode==2){
          int n = rrow & (NATOM-1);
          C[ci] += sigm(b2f(gate[(long long)n*gate_ld + gate_coloff + col])) * v;
        } else if (mode==3) Cu[ci] = f2b(v);
        else if (mode==4) Cu[ci] = f2b(fmaxf(v, 0.f));
        else C[ci] = v;
      }
    }
  }
}

__global__ __launch_bounds__(128) void tokagg_kernel(const int* __restrict__ tok_idx,
    const float* __restrict__ qtok, float* __restrict__ out)
{
  int t = blockIdx.x;
  int lo=0, hi=NATOM;
  while (lo<hi){ int mid=(lo+hi)>>1; if (tok_idx[mid] < t) lo=mid+1; else hi=mid; }
  int start = lo;
  lo = start; hi = NATOM;
  while (lo<hi){ int mid=(lo+hi)>>1; if (tok_idx[mid] <= t) lo=mid+1; else hi=mid; }
  int end = lo;
  int cnt = end - start;
  float inv = 1.0f / (float)(cnt>0 ? cnt : 1);
  for (int s=0; s<SD; s++)
    for (int c=threadIdx.x; c<CTD; c+=128){
      float acc = 0.f;
      for (int n=start; n<end; n++) acc += qtok[((long long)(s*NATOM+n))*CTD + c];
      out[(long long)(s*TT + t)*CTD + c] = acc*inv;
    }
}

extern "C" void kernel_launch(void* const* d_in, const int* in_sizes, int n_in,
                              void* d_out, int out_size, void* d_ws, size_t ws_size,
                              hipStream_t stream)
{
  const float* atom_single = (const float*)d_in[0];
  const float* atom_proj   = (const float*)d_in[1];
  const float* atom_pair   = (const float*)d_in[2];
  const float* mask        = (const float*)d_in[3];
  const int*   tok_idx     = (const int*)  d_in[4];
  const float* aln_s_w     = (const float*)d_in[5];
  const float* aln_s_b     = (const float*)d_in[6];
  const float* pair_ln_w   = (const float*)d_in[14];
  const float* pair_ln_b   = (const float*)d_in[15];
  const float* pair_w      = (const float*)d_in[16];
  const float* t_aln_s_w   = (const float*)d_in[21];
  const float* t_aln_s_b   = (const float*)d_in[22];

  char* wsb = (char*)d_ws;
  ushortx* W3T    = (ushortx*)(wsb+OFFB_W3T);
  float*   B3     = (float*)  (wsb+OFFB_B3);
  ushortx* WQKVGT = (ushortx*)(wsb+OFFB_WQKVGT);
  float*   BQ     = (float*)  (wsb+OFFB_BQ);
  ushortx* WOUTT  = (ushortx*)(wsb+OFFB_WOUTT);
  ushortx* WABT   = (ushortx*)(wsb+OFFB_WABT);
  ushortx* WTOUTT = (ushortx*)(wsb+OFFB_WTOUTT);
  ushortx* WTOKT  = (ushortx*)(wsb+OFFB_WTOKT);
  ushortx* A1     = (ushortx*)(wsb+OFFB_A1);
  ushortx* SNP    = (ushortx*)(wsb+OFFB_SNP);
  float*   Af     = (float*)  (wsb+OFFB_A);
  ushortx* QKVG   = (ushortx*)(wsb+OFFB_QKVG);
  ushortx* ZB     = (ushortx*)(wsb+OFFB_ZB);
  float*   QTOK   = (float*)  (wsb+OFFB_QTOK);

  WPtrs P;
  P.aln_gate_w=(const float*)d_in[7];  P.aln_gate_b=(const float*)d_in[8];  P.aln_shift_w=(const float*)d_in[9];
  P.og_w=(const float*)d_in[19]; P.og_b=(const float*)d_in[20];
  P.t_aln_gate_w=(const float*)d_in[23]; P.t_aln_gate_b=(const float*)d_in[24]; P.t_aln_shift_w=(const float*)d_in[25];
  P.t_og_w=(const float*)d_in[29]; P.t_og_b=(const float*)d_in[30];
  P.q_w=(const float*)d_in[10]; P.q_b=(const float*)d_in[11]; P.k_w=(const float*)d_in[12];
  P.v_w=(const float*)d_in[13]; P.gate_w=(const float*)d_in[17]; P.out_w=(const float*)d_in[18];
  P.t_a_w=(const float*)d_in[26]; P.t_b_w=(const float*)d_in[27]; P.t_out_w=(const float*)d_in[28];
  P.tok_w=(const float*)d_in[31];

  // prologue: pack (3471) + copy (2048) + zb (1024) in one launch
  prologue_kernel<<<6543,256,0,stream>>>(P, wsb, atom_single, atom_pair,
      pair_ln_w, pair_ln_b, pair_w);
  // snp[which] = (LN(atom_proj)*w_which+b_which) @ W3[which]^T + b3[which]  -> bf16
  gemm_f<4,64><<<dim3(6,32,6),256,0,stream>>>(atom_proj, 0, W3T, 49152ll,
      B3, 384ll, SNP, 786432ll, NATOM, 384, 128, 3, nullptr, 0, 0,
      aln_s_w, aln_s_b, t_aln_s_w, t_aln_s_b);
  // qkvg0 = modln_0(a) @ [q|k|v|gate] + [q_b|0|0|0]  -> bf16
  gemm_f<1,64><<<dim3(8,64,1),256,0,stream>>>(Af, 0, WQKVGT, 0,
      BQ, 0, QKVG, 0, MR, 512, 128, 3, nullptr, 0, 0,
      SNP, nullptr, nullptr, nullptr);

  for (int i=0;i<NBI;i++){
    const ushortx* snpA = SNP + (long long)(2*i)*786432;
    const ushortx* snpT = SNP + (long long)(2*i+1)*786432;
    attn_kernel<<<dim3(64,8,2),256,0,stream>>>(QKVG, ZB + (long long)i*2097152, mask, A1);
    if (i < NBI-1){
      postattn_kernel<0><<<256,256,0,stream>>>(Af, A1,
          WOUTT + (long long)i*16384, WABT + (long long)i*65536, WTOUTT + (long long)i*32768,
          WQKVGT + (long long)(i+1)*65536, BQ + (long long)(i+1)*512,
          snpA, snpT, SNP + (long long)(2*(i+1))*786432, QKVG, nullptr);
    } else {
      postattn_kernel<1><<<256,256,0,stream>>>(Af, A1,
          WOUTT + (long long)i*16384, WABT + (long long)i*65536, WTOUTT + (long long)i*32768,
          WTOKT, nullptr, snpA, snpT, nullptr, nullptr, QTOK);
    }
  }
  tokagg_kernel<<<TT,128,0,stream>>>(tok_idx, QTOK, (float*)d_out);
}